// Round 28
// baseline (113.416 us; speedup 1.0000x reference)
//
#include <hip/hip_runtime.h>
#include <hip/hip_fp16.h>

#define N_NODES 50000
#define N_EDGES 800000
#define IN_F    128
#define OUT_F   32
#define HEADS   4
#define EDGE_DIM 8
#define LRELU_ALPHA 0.2f

#define EPB 2048                      // edges per binsort block
#define BT  1024                      // binsort threads
#define EPT (EPB / BT)                // 2 edges per thread
#define NBUCK 98                      // buckets of 512 nodes (dst>>9)
#define NBLK_A ((N_EDGES + EPB - 1) / EPB)  // 391
#define NODES_PER_BUCK 512
#define CAP 10240                     // staging capacity per bucket (avg 8163)

// native clang vector types
typedef float    floatx4 __attribute__((ext_vector_type(4)));
typedef unsigned uintx4  __attribute__((ext_vector_type(4)));
typedef short    short4v __attribute__((ext_vector_type(4)));
typedef short    short8v __attribute__((ext_vector_type(8)));
typedef float    f32x4   __attribute__((ext_vector_type(4)));

// round-to-nearest-even f32 -> bf16 (as ushort in low bits)
__device__ __forceinline__ unsigned f2bf(float f) {
  unsigned u = __float_as_uint(f);
  return (u + 0x7fffu + ((u >> 16) & 1u)) >> 16;
}

// ---------------------------------------------------------------------------
// K0: one-time W transpose+convert: wtg[h*32+o][i] = bf16(W[h,i,o]);
// also seeds bfill.
// ---------------------------------------------------------------------------
__global__ __launch_bounds__(128) void k_wprep(
    const float* __restrict__ W, unsigned short* __restrict__ wtg,
    unsigned* __restrict__ bfill) {
  const int row = blockIdx.x;           // h*32 + o
  const int i = threadIdx.x;            // 0..127
  if (row == 0 && i < NBUCK) bfill[i] = (unsigned)(i * CAP);
  const float v = W[(row >> 5) * (IN_F * OUT_F) + i * OUT_F + (row & 31)];
  wtg[row * 128 + i] = (unsigned short)f2bf(v);
}

// ---------------------------------------------------------------------------
// K1: MFMA bf16 GEMM + fused alpha epilogue (R25, unchanged).
// ---------------------------------------------------------------------------
__global__ __launch_bounds__(256) void k_transform(
    const float* __restrict__ x, const unsigned short* __restrict__ wtg,
    const float* __restrict__ a, unsigned* __restrict__ xtb,
    float* __restrict__ alpha_src, float* __restrict__ alpha_dst) {
  __shared__ short sxb[64][138];
  __shared__ short wt[128][132];      // later reused as xp[64][66] dwords
  const int t = threadIdx.x;
  const int n0 = blockIdx.x * 64;

#pragma unroll
  for (int r = 0; r < 8; ++r) {
    const int f = r * 256 + t;
    const int row = f >> 4;
    const int c8 = (f & 15) * 8;
    const short8v v =
        *reinterpret_cast<const short8v*>(&wtg[row * 128 + c8]);
    *reinterpret_cast<short8v*>(&wt[row][c8]) = v;
  }

#pragma unroll
  for (int r = 0; r < 8; ++r) {
    const int f = r * 256 + t;
    const int node = f >> 5;
    const int i4 = (f & 31) * 4;
    const int n = n0 + node;
    float4 v = make_float4(0.f, 0.f, 0.f, 0.f);
    if (n < N_NODES) v = *reinterpret_cast<const float4*>(&x[(size_t)n * 128 + i4]);
    short4v s4;
    s4.x = (short)f2bf(v.x);
    s4.y = (short)f2bf(v.y);
    s4.z = (short)f2bf(v.z);
    s4.w = (short)f2bf(v.w);
    *reinterpret_cast<short4v*>(&sxb[node][i4]) = s4;
  }
  __syncthreads();

  const int w = t >> 6;
  const int lane = t & 63;
  const int r16 = lane & 15;
  const int kg = lane >> 4;

  f32x4 acc[8];
#pragma unroll
  for (int nt = 0; nt < 8; ++nt) acc[nt] = (f32x4)(0.f);

#pragma unroll
  for (int kk = 0; kk < 4; ++kk) {
    const short8v afrag =
        *reinterpret_cast<const short8v*>(&sxb[w * 16 + r16][kk * 32 + kg * 8]);
#pragma unroll
    for (int nt = 0; nt < 8; ++nt) {
      const short8v bfrag =
          *reinterpret_cast<const short8v*>(&wt[nt * 16 + r16][kk * 32 + kg * 8]);
      acc[nt] = __builtin_amdgcn_mfma_f32_16x16x32_bf16(afrag, bfrag, acc[nt],
                                                        0, 0, 0);
    }
  }

  __syncthreads();  // all waves done reading wt -> safe to reuse as xp
  unsigned* __restrict__ xp = reinterpret_cast<unsigned*>(&wt[0][0]);

#pragma unroll
  for (int nt = 0; nt < 8; ++nt) {
#pragma unroll
    for (int reg = 0; reg < 4; ++reg) {
      const float v = acc[nt][reg];
      const float vp = __shfl_xor(v, 1, 64);
      if (!(lane & 1)) {
        const int nodeL = w * 16 + kg * 4 + reg;
        const int node = n0 + nodeL;
        const unsigned u = f2bf(v) | (f2bf(vp) << 16);
        xp[nodeL * 66 + nt * 8 + (r16 >> 1)] = u;
        if (node < N_NODES) {
          xtb[(size_t)node * 64 + nt * 8 + (r16 >> 1)] = u;
        }
      }
    }
  }
  __syncthreads();

  {
    const int nodeL = t >> 2;
    const int q = t & 3;
    const int node = n0 + nodeL;
    if (node < N_NODES) {
      const unsigned* __restrict__ row = &xp[nodeL * 66 + q * 16];
      const float* __restrict__ as = &a[q * 72];
      const float* __restrict__ ad = &a[q * 72 + 32];
      float s = 0.f, d = 0.f;
#pragma unroll
      for (int j = 0; j < 16; ++j) {
        const unsigned u = row[j];
        const float lo = __uint_as_float(u << 16);
        const float hi = __uint_as_float(u & 0xffff0000u);
        s = fmaf(lo, as[2 * j], s);
        s = fmaf(hi, as[2 * j + 1], s);
        d = fmaf(lo, ad[2 * j], d);
        d = fmaf(hi, ad[2 * j + 1], d);
      }
      alpha_src[node * 4 + q] = s;
      alpha_dst[node * 4 + q] = d;
    }
  }
}

// ---------------------------------------------------------------------------
// entry builder: {src, fp16x2(s0,s1), fp16x2(s2,s3), dst}
// ---------------------------------------------------------------------------
__device__ __forceinline__ uintx4 make_entry(
    int e, int src, int dst, const float* __restrict__ ea,
    const float* __restrict__ a, const float* __restrict__ alpha_src,
    const float* __restrict__ alpha_dst) {
  const floatx4 ev0 = __builtin_nontemporal_load(
      reinterpret_cast<const floatx4*>(&ea[(size_t)e * EDGE_DIM]));
  const floatx4 ev1 = __builtin_nontemporal_load(
      reinterpret_cast<const floatx4*>(&ea[(size_t)e * EDGE_DIM + 4]));
  const float4 als = *reinterpret_cast<const float4*>(&alpha_src[src * 4]);
  const float4 ald = *reinterpret_cast<const float4*>(&alpha_dst[dst * 4]);
  const float* alsp = reinterpret_cast<const float*>(&als);
  const float* aldp = reinterpret_cast<const float*>(&ald);
  unsigned sh[4];
#pragma unroll
  for (int h = 0; h < HEADS; ++h) {
    float s = alsp[h] + aldp[h];
    const float* ae = &a[h * 72 + 64];
    s = fmaf(ev0.x, ae[0], s);
    s = fmaf(ev0.y, ae[1], s);
    s = fmaf(ev0.z, ae[2], s);
    s = fmaf(ev0.w, ae[3], s);
    s = fmaf(ev1.x, ae[4], s);
    s = fmaf(ev1.y, ae[5], s);
    s = fmaf(ev1.z, ae[6], s);
    s = fmaf(ev1.w, ae[7], s);
    s = s > 0.f ? s : LRELU_ALPHA * s;
    sh[h] = (unsigned)__half_as_ushort(__float2half(s));
  }
  uintx4 ent;
  ent.x = (unsigned)src;
  ent.y = sh[0] | (sh[1] << 16);
  ent.z = sh[2] | (sh[3] << 16);
  ent.w = (unsigned)dst;
  return ent;
}

// ---------------------------------------------------------------------------
// K3: bucket binsort — direct scatter (R27, unchanged).
// ---------------------------------------------------------------------------
__global__ __launch_bounds__(BT) void k_binsort(
    const int* __restrict__ ei, const float* __restrict__ ea,
    const float* __restrict__ a, const float* __restrict__ alpha_src,
    const float* __restrict__ alpha_dst, unsigned* __restrict__ bfill,
    uintx4* __restrict__ stage) {
  __shared__ unsigned lhist[128];
  __shared__ unsigned gb[128];
  const int t = threadIdx.x;
  const int e0 = blockIdx.x * EPB;

  if (t < 128) lhist[t] = 0u;
  __syncthreads();

  uintx4 ent[EPT];
  int bk[EPT];
  int lpos[EPT];
#pragma unroll
  for (int k = 0; k < EPT; ++k) {
    const int e = e0 + k * BT + t;
    bk[k] = -1;
    if (e < N_EDGES) {
      const int src = __builtin_nontemporal_load(&ei[e]);
      const int dst = __builtin_nontemporal_load(&ei[N_EDGES + e]);
      ent[k] = make_entry(e, src, dst, ea, a, alpha_src, alpha_dst);
      bk[k] = dst >> 9;
      lpos[k] = (int)atomicAdd(&lhist[bk[k]], 1u);
    }
  }
  __syncthreads();

  if (t < NBUCK) {
    const unsigned cnt = lhist[t];
    gb[t] = cnt ? atomicAdd(&bfill[t], cnt) : 0u;
  }
  __syncthreads();

#pragma unroll
  for (int k = 0; k < EPT; ++k) {
    if (bk[k] >= 0) {
      stage[gb[bk[k]] + (unsigned)lpos[k]] = ent[k];
    }
  }
}

// ---------------------------------------------------------------------------
// K4: place (bucket-start scan fused). Pass 1: per-node counts -> block scan
// -> rs + LDS cursors. Pass 2: place into single-writer CSR region.
// ---------------------------------------------------------------------------
__global__ __launch_bounds__(1024) void k_place(
    const unsigned* __restrict__ bfill, const uintx4* __restrict__ stage,
    unsigned* __restrict__ rs, uintx4* __restrict__ csr) {
  __shared__ unsigned lbuf[NODES_PER_BUCK];
  __shared__ unsigned wsum[8];
  __shared__ unsigned bscan[128];
  const int b = blockIdx.x;
  const int t = threadIdx.x;
  const int node0 = b << 9;
  const int nn = min(NODES_PER_BUCK, N_NODES - node0);
  const unsigned base = (unsigned)(b * CAP);

  if (t < 128) {
    bscan[t] = (t < NBUCK) ? (bfill[t] - (unsigned)(t * CAP)) : 0u;
  }
  __syncthreads();
#pragma unroll
  for (int off = 1; off < 128; off <<= 1) {
    unsigned v = 0u;
    if (t < 128 && t >= off) v = bscan[t - off];
    __syncthreads();
    if (t < 128) bscan[t] += v;
    __syncthreads();
  }
  const unsigned cnt = bfill[b] - base;
  const unsigned bs = (b == 0) ? 0u : bscan[b - 1];

  if (t < NODES_PER_BUCK) lbuf[t] = 0u;
  __syncthreads();

  for (unsigned i = t; i < cnt; i += 1024) {
    const unsigned dst = __builtin_nontemporal_load(&stage[base + i]).w;
    atomicAdd(&lbuf[dst - (unsigned)node0], 1u);
  }
  __syncthreads();

  const unsigned c = (t < NODES_PER_BUCK) ? lbuf[t] : 0u;
  unsigned incl = c;
  const int lane = t & 63;
#pragma unroll
  for (int off = 1; off < 64; off <<= 1) {
    const unsigned n = __shfl_up(incl, off, 64);
    if (lane >= off) incl += n;
  }
  if (t < NODES_PER_BUCK && lane == 63) wsum[t >> 6] = incl;
  __syncthreads();
  if (t < 8) {
    const unsigned wv = wsum[t];
    unsigned wincl = wv;
#pragma unroll
    for (int off = 1; off < 8; off <<= 1) {
      const unsigned n = __shfl_up(wincl, off, 64);
      if (t >= off) wincl += n;
    }
    wsum[t] = wincl - wv;
  }
  __syncthreads();
  if (t < NODES_PER_BUCK) {
    const unsigned excl = incl - c + wsum[t >> 6];
    lbuf[t] = bs + excl;
    if (t < nn) rs[node0 + t] = bs + excl;
  }
  if (b == NBUCK - 1 && t == 0) rs[N_NODES] = N_EDGES;
  __syncthreads();

  for (unsigned i = t; i < cnt; i += 1024) {
    const uintx4 ent = __builtin_nontemporal_load(&stage[base + i]);
    const unsigned slot = atomicAdd(&lbuf[ent.w - (unsigned)node0], 1u);
    csr[slot] = ent;
  }
}

// ---------------------------------------------------------------------------
// K5: agg — lane-role swap + degree-bounded accumulate (round-28): the 16
// AGG_STEPs are gated in groups of 4 by wave-uniform `rem = deg - r*16`
// (dst-uniform -> scalar branch). Skipped groups are all-pad (w=0 already
// summed into lsum); partially-valid groups run in full (pad w=0 exact).
// Cuts ~2/3 of the ~33% pad gather/FMA work.
// ---------------------------------------------------------------------------
__device__ __forceinline__ float ent_score(const uintx4& ent, int h) {
  const unsigned uu = (h < 2) ? ent.y : ent.z;
  const unsigned us = (h & 1) ? (uu >> 16) : (uu & 0xffffu);
  return __half2float(__ushort_as_half((unsigned short)us));
}

__global__ __launch_bounds__(256) void k_agg(
    const unsigned* __restrict__ rs, const uintx4* __restrict__ csr,
    const unsigned* __restrict__ xtb, float* __restrict__ out) {
  const int lane = threadIdx.x & 63;
  const int dst = (int)((blockIdx.x * (unsigned)blockDim.x + threadIdx.x) >> 6);
  if (dst >= N_NODES) return;

  const unsigned j0 = rs[dst];
  const unsigned j1 = rs[dst + 1];
  const int deg = (int)(j1 - j0);

  float a0 = 0.f, a1 = 0.f, lsum = 0.f;

  if (deg > 0) {
    const int rounds = (deg + 15) >> 4;
    const int eL = lane & 15;   // edge slot
    const int hB = lane >> 4;   // head (same role in score & accum)

    const uintx4 pad = {0u, 0xfc00fc00u, 0xfc00fc00u, 0u};

    for (int r = 0; r < rounds; ++r) {
      const int j = (int)j0 + r * 16 + eL;
      const uintx4 ent =
          (j < (int)j1) ? __builtin_nontemporal_load(&csr[j]) : pad;
      const float w = __expf(ent_score(ent, hB));  // pad: exp(-inf)=0
      lsum += w;
      const int sx = (int)ent.x;
      const int rem = deg - r * 16;   // wave-uniform (>0)

      int ssrc[16];
#pragma unroll
      for (int jj = 0; jj < 16; ++jj)
        ssrc[jj] = __builtin_amdgcn_readlane(sx, jj);
#define AGG_STEP(JJ)                                                         \
  {                                                                          \
    const unsigned u = xtb[(size_t)ssrc[JJ] * 64 + lane];                    \
    const float wj = __int_as_float(__builtin_amdgcn_ds_swizzle(             \
        __float_as_int(w), ((JJ) << 5) | 0x10));                             \
    a0 = fmaf(wj, __uint_as_float(u << 16), a0);                             \
    a1 = fmaf(wj, __uint_as_float(u & 0xffff0000u), a1);                     \
  }
      AGG_STEP(0)  AGG_STEP(1)  AGG_STEP(2)  AGG_STEP(3)
      if (rem > 4) {
        AGG_STEP(4)  AGG_STEP(5)  AGG_STEP(6)  AGG_STEP(7)
        if (rem > 8) {
          AGG_STEP(8)  AGG_STEP(9)  AGG_STEP(10) AGG_STEP(11)
          if (rem > 12) {
            AGG_STEP(12) AGG_STEP(13) AGG_STEP(14) AGG_STEP(15)
          }
        }
      }
#undef AGG_STEP
    }
    lsum += __shfl_xor(lsum, 1, 64);
    lsum += __shfl_xor(lsum, 2, 64);
    lsum += __shfl_xor(lsum, 4, 64);
    lsum += __shfl_xor(lsum, 8, 64);
  }

  const float inv = 1.0f / (lsum + 1e-10f);
  __builtin_nontemporal_store(a0 * inv, &out[(size_t)dst * 128 + lane * 2 + 0]);
  __builtin_nontemporal_store(a1 * inv, &out[(size_t)dst * 128 + lane * 2 + 1]);
}

extern "C" void kernel_launch(void* const* d_in, const int* in_sizes, int n_in,
                              void* d_out, int out_size, void* d_ws,
                              size_t ws_size, hipStream_t stream) {
  const float* x = (const float*)d_in[0];
  const int* ei = (const int*)d_in[1];
  const float* ea = (const float*)d_in[2];
  const float* W = (const float*)d_in[3];
  const float* a = (const float*)d_in[4];
  float* out = (float*)d_out;

  // workspace layout
  char* p = (char*)d_ws;
  unsigned* xtb = (unsigned*)p;     p += (size_t)N_NODES * 64 * 4;      // 12.8 MB
  uintx4* csr = (uintx4*)p;         p += (size_t)N_EDGES * 16;          // 12.8 MB
  uintx4* stage = (uintx4*)p;       p += (size_t)NBUCK * CAP * 16;      // 16.1 MB
  float* alpha_src = (float*)p;     p += (size_t)N_NODES * 4 * 4;       // 0.8 MB
  float* alpha_dst = (float*)p;     p += (size_t)N_NODES * 4 * 4;       // 0.8 MB
  unsigned* rs = (unsigned*)p;      p += (size_t)(N_NODES + 1) * 4;     // 0.2 MB
  unsigned* bfill = (unsigned*)p;   p += 128 * 4;
  unsigned short* wtg = (unsigned short*)p; p += 128 * 128 * 2;         // 32 KB

  k_wprep<<<128, 128, 0, stream>>>(W, wtg, bfill);
  k_transform<<<(N_NODES + 63) / 64, 256, 0, stream>>>(x, wtg, a, xtb,
                                                       alpha_src, alpha_dst);
  k_binsort<<<NBLK_A, BT, 0, stream>>>(ei, ea, a, alpha_src, alpha_dst, bfill,
                                       stage);
  k_place<<<NBUCK, 1024, 0, stream>>>(bfill, stage, rs, csr);
  k_agg<<<(N_NODES * 64 + 255) / 256, 256, 0, stream>>>(rs, csr, xtb, out);
}

// Round 29
// 109.050 us; speedup vs baseline: 1.0400x; 1.0400x over previous
//
#include <hip/hip_runtime.h>
#include <hip/hip_fp16.h>

#define N_NODES 50000
#define N_EDGES 800000
#define IN_F    128
#define OUT_F   32
#define HEADS   4
#define EDGE_DIM 8
#define LRELU_ALPHA 0.2f

#define EPB 2048                      // edges per binsort block
#define BT  1024                      // binsort threads
#define EPT (EPB / BT)                // 2 edges per thread
#define NBUCK 98                      // buckets of 512 nodes (dst>>9)
#define NBLK_A ((N_EDGES + EPB - 1) / EPB)  // 391
#define NODES_PER_BUCK 512
#define CAP 10240                     // staging capacity per bucket (avg 8163)

// native clang vector types
typedef float    floatx4 __attribute__((ext_vector_type(4)));
typedef unsigned uintx4  __attribute__((ext_vector_type(4)));
typedef short    short4v __attribute__((ext_vector_type(4)));
typedef short    short8v __attribute__((ext_vector_type(8)));
typedef float    f32x4   __attribute__((ext_vector_type(4)));

// round-to-nearest-even f32 -> bf16 (as ushort in low bits)
__device__ __forceinline__ unsigned f2bf(float f) {
  unsigned u = __float_as_uint(f);
  return (u + 0x7fffu + ((u >> 16) & 1u)) >> 16;
}

// ---------------------------------------------------------------------------
// K0: one-time W transpose+convert: wtg[h*32+o][i] = bf16(W[h,i,o]);
// also seeds bfill.
// ---------------------------------------------------------------------------
__global__ __launch_bounds__(128) void k_wprep(
    const float* __restrict__ W, unsigned short* __restrict__ wtg,
    unsigned* __restrict__ bfill) {
  const int row = blockIdx.x;           // h*32 + o
  const int i = threadIdx.x;            // 0..127
  if (row == 0 && i < NBUCK) bfill[i] = (unsigned)(i * CAP);
  const float v = W[(row >> 5) * (IN_F * OUT_F) + i * OUT_F + (row & 31)];
  wtg[row * 128 + i] = (unsigned short)f2bf(v);
}

// ---------------------------------------------------------------------------
// K1: MFMA bf16 GEMM + fused alpha epilogue (R25, unchanged).
// ---------------------------------------------------------------------------
__global__ __launch_bounds__(256) void k_transform(
    const float* __restrict__ x, const unsigned short* __restrict__ wtg,
    const float* __restrict__ a, unsigned* __restrict__ xtb,
    float* __restrict__ alpha_src, float* __restrict__ alpha_dst) {
  __shared__ short sxb[64][138];
  __shared__ short wt[128][132];      // later reused as xp[64][66] dwords
  const int t = threadIdx.x;
  const int n0 = blockIdx.x * 64;

#pragma unroll
  for (int r = 0; r < 8; ++r) {
    const int f = r * 256 + t;
    const int row = f >> 4;
    const int c8 = (f & 15) * 8;
    const short8v v =
        *reinterpret_cast<const short8v*>(&wtg[row * 128 + c8]);
    *reinterpret_cast<short8v*>(&wt[row][c8]) = v;
  }

#pragma unroll
  for (int r = 0; r < 8; ++r) {
    const int f = r * 256 + t;
    const int node = f >> 5;
    const int i4 = (f & 31) * 4;
    const int n = n0 + node;
    float4 v = make_float4(0.f, 0.f, 0.f, 0.f);
    if (n < N_NODES) v = *reinterpret_cast<const float4*>(&x[(size_t)n * 128 + i4]);
    short4v s4;
    s4.x = (short)f2bf(v.x);
    s4.y = (short)f2bf(v.y);
    s4.z = (short)f2bf(v.z);
    s4.w = (short)f2bf(v.w);
    *reinterpret_cast<short4v*>(&sxb[node][i4]) = s4;
  }
  __syncthreads();

  const int w = t >> 6;
  const int lane = t & 63;
  const int r16 = lane & 15;
  const int kg = lane >> 4;

  f32x4 acc[8];
#pragma unroll
  for (int nt = 0; nt < 8; ++nt) acc[nt] = (f32x4)(0.f);

#pragma unroll
  for (int kk = 0; kk < 4; ++kk) {
    const short8v afrag =
        *reinterpret_cast<const short8v*>(&sxb[w * 16 + r16][kk * 32 + kg * 8]);
#pragma unroll
    for (int nt = 0; nt < 8; ++nt) {
      const short8v bfrag =
          *reinterpret_cast<const short8v*>(&wt[nt * 16 + r16][kk * 32 + kg * 8]);
      acc[nt] = __builtin_amdgcn_mfma_f32_16x16x32_bf16(afrag, bfrag, acc[nt],
                                                        0, 0, 0);
    }
  }

  __syncthreads();  // all waves done reading wt -> safe to reuse as xp
  unsigned* __restrict__ xp = reinterpret_cast<unsigned*>(&wt[0][0]);

#pragma unroll
  for (int nt = 0; nt < 8; ++nt) {
#pragma unroll
    for (int reg = 0; reg < 4; ++reg) {
      const float v = acc[nt][reg];
      const float vp = __shfl_xor(v, 1, 64);
      if (!(lane & 1)) {
        const int nodeL = w * 16 + kg * 4 + reg;
        const int node = n0 + nodeL;
        const unsigned u = f2bf(v) | (f2bf(vp) << 16);
        xp[nodeL * 66 + nt * 8 + (r16 >> 1)] = u;
        if (node < N_NODES) {
          xtb[(size_t)node * 64 + nt * 8 + (r16 >> 1)] = u;
        }
      }
    }
  }
  __syncthreads();

  {
    const int nodeL = t >> 2;
    const int q = t & 3;
    const int node = n0 + nodeL;
    if (node < N_NODES) {
      const unsigned* __restrict__ row = &xp[nodeL * 66 + q * 16];
      const float* __restrict__ as = &a[q * 72];
      const float* __restrict__ ad = &a[q * 72 + 32];
      float s = 0.f, d = 0.f;
#pragma unroll
      for (int j = 0; j < 16; ++j) {
        const unsigned u = row[j];
        const float lo = __uint_as_float(u << 16);
        const float hi = __uint_as_float(u & 0xffff0000u);
        s = fmaf(lo, as[2 * j], s);
        s = fmaf(hi, as[2 * j + 1], s);
        d = fmaf(lo, ad[2 * j], d);
        d = fmaf(hi, ad[2 * j + 1], d);
      }
      alpha_src[node * 4 + q] = s;
      alpha_dst[node * 4 + q] = d;
    }
  }
}

// ---------------------------------------------------------------------------
// entry builder: {src, fp16x2(s0,s1), fp16x2(s2,s3), dst}
// ---------------------------------------------------------------------------
__device__ __forceinline__ uintx4 make_entry(
    int e, int src, int dst, const float* __restrict__ ea,
    const float* __restrict__ a, const float* __restrict__ alpha_src,
    const float* __restrict__ alpha_dst) {
  const floatx4 ev0 = __builtin_nontemporal_load(
      reinterpret_cast<const floatx4*>(&ea[(size_t)e * EDGE_DIM]));
  const floatx4 ev1 = __builtin_nontemporal_load(
      reinterpret_cast<const floatx4*>(&ea[(size_t)e * EDGE_DIM + 4]));
  const float4 als = *reinterpret_cast<const float4*>(&alpha_src[src * 4]);
  const float4 ald = *reinterpret_cast<const float4*>(&alpha_dst[dst * 4]);
  const float* alsp = reinterpret_cast<const float*>(&als);
  const float* aldp = reinterpret_cast<const float*>(&ald);
  unsigned sh[4];
#pragma unroll
  for (int h = 0; h < HEADS; ++h) {
    float s = alsp[h] + aldp[h];
    const float* ae = &a[h * 72 + 64];
    s = fmaf(ev0.x, ae[0], s);
    s = fmaf(ev0.y, ae[1], s);
    s = fmaf(ev0.z, ae[2], s);
    s = fmaf(ev0.w, ae[3], s);
    s = fmaf(ev1.x, ae[4], s);
    s = fmaf(ev1.y, ae[5], s);
    s = fmaf(ev1.z, ae[6], s);
    s = fmaf(ev1.w, ae[7], s);
    s = s > 0.f ? s : LRELU_ALPHA * s;
    sh[h] = (unsigned)__half_as_ushort(__float2half(s));
  }
  uintx4 ent;
  ent.x = (unsigned)src;
  ent.y = sh[0] | (sh[1] << 16);
  ent.z = sh[2] | (sh[3] << 16);
  ent.w = (unsigned)dst;
  return ent;
}

// ---------------------------------------------------------------------------
// K3: bucket binsort — direct scatter (R27, unchanged).
// ---------------------------------------------------------------------------
__global__ __launch_bounds__(BT) void k_binsort(
    const int* __restrict__ ei, const float* __restrict__ ea,
    const float* __restrict__ a, const float* __restrict__ alpha_src,
    const float* __restrict__ alpha_dst, unsigned* __restrict__ bfill,
    uintx4* __restrict__ stage) {
  __shared__ unsigned lhist[128];
  __shared__ unsigned gb[128];
  const int t = threadIdx.x;
  const int e0 = blockIdx.x * EPB;

  if (t < 128) lhist[t] = 0u;
  __syncthreads();

  uintx4 ent[EPT];
  int bk[EPT];
  int lpos[EPT];
#pragma unroll
  for (int k = 0; k < EPT; ++k) {
    const int e = e0 + k * BT + t;
    bk[k] = -1;
    if (e < N_EDGES) {
      const int src = __builtin_nontemporal_load(&ei[e]);
      const int dst = __builtin_nontemporal_load(&ei[N_EDGES + e]);
      ent[k] = make_entry(e, src, dst, ea, a, alpha_src, alpha_dst);
      bk[k] = dst >> 9;
      lpos[k] = (int)atomicAdd(&lhist[bk[k]], 1u);
    }
  }
  __syncthreads();

  if (t < NBUCK) {
    const unsigned cnt = lhist[t];
    gb[t] = cnt ? atomicAdd(&bfill[t], cnt) : 0u;
  }
  __syncthreads();

#pragma unroll
  for (int k = 0; k < EPT; ++k) {
    if (bk[k] >= 0) {
      stage[gb[bk[k]] + (unsigned)lpos[k]] = ent[k];
    }
  }
}

// ---------------------------------------------------------------------------
// K4: place (bucket-start scan fused). Pass 1: per-node counts -> block scan
// -> rs + LDS cursors. Pass 2: place into single-writer CSR region.
// ---------------------------------------------------------------------------
__global__ __launch_bounds__(1024) void k_place(
    const unsigned* __restrict__ bfill, const uintx4* __restrict__ stage,
    unsigned* __restrict__ rs, uintx4* __restrict__ csr) {
  __shared__ unsigned lbuf[NODES_PER_BUCK];
  __shared__ unsigned wsum[8];
  __shared__ unsigned bscan[128];
  const int b = blockIdx.x;
  const int t = threadIdx.x;
  const int node0 = b << 9;
  const int nn = min(NODES_PER_BUCK, N_NODES - node0);
  const unsigned base = (unsigned)(b * CAP);

  if (t < 128) {
    bscan[t] = (t < NBUCK) ? (bfill[t] - (unsigned)(t * CAP)) : 0u;
  }
  __syncthreads();
#pragma unroll
  for (int off = 1; off < 128; off <<= 1) {
    unsigned v = 0u;
    if (t < 128 && t >= off) v = bscan[t - off];
    __syncthreads();
    if (t < 128) bscan[t] += v;
    __syncthreads();
  }
  const unsigned cnt = bfill[b] - base;
  const unsigned bs = (b == 0) ? 0u : bscan[b - 1];

  if (t < NODES_PER_BUCK) lbuf[t] = 0u;
  __syncthreads();

  for (unsigned i = t; i < cnt; i += 1024) {
    const unsigned dst = __builtin_nontemporal_load(&stage[base + i]).w;
    atomicAdd(&lbuf[dst - (unsigned)node0], 1u);
  }
  __syncthreads();

  const unsigned c = (t < NODES_PER_BUCK) ? lbuf[t] : 0u;
  unsigned incl = c;
  const int lane = t & 63;
#pragma unroll
  for (int off = 1; off < 64; off <<= 1) {
    const unsigned n = __shfl_up(incl, off, 64);
    if (lane >= off) incl += n;
  }
  if (t < NODES_PER_BUCK && lane == 63) wsum[t >> 6] = incl;
  __syncthreads();
  if (t < 8) {
    const unsigned wv = wsum[t];
    unsigned wincl = wv;
#pragma unroll
    for (int off = 1; off < 8; off <<= 1) {
      const unsigned n = __shfl_up(wincl, off, 64);
      if (t >= off) wincl += n;
    }
    wsum[t] = wincl - wv;
  }
  __syncthreads();
  if (t < NODES_PER_BUCK) {
    const unsigned excl = incl - c + wsum[t >> 6];
    lbuf[t] = bs + excl;
    if (t < nn) rs[node0 + t] = bs + excl;
  }
  if (b == NBUCK - 1 && t == 0) rs[N_NODES] = N_EDGES;
  __syncthreads();

  for (unsigned i = t; i < cnt; i += 1024) {
    const uintx4 ent = __builtin_nontemporal_load(&stage[base + i]);
    const unsigned slot = atomicAdd(&lbuf[ent.w - (unsigned)node0], 1u);
    csr[slot] = ent;
  }
}

// ---------------------------------------------------------------------------
// K5: agg — lane-role swap (R25/R27 version; R28 degree-gating reverted:
// agg is latency-bound, gating broke the batched-gather MLP).
// ---------------------------------------------------------------------------
__device__ __forceinline__ float ent_score(const uintx4& ent, int h) {
  const unsigned uu = (h < 2) ? ent.y : ent.z;
  const unsigned us = (h & 1) ? (uu >> 16) : (uu & 0xffffu);
  return __half2float(__ushort_as_half((unsigned short)us));
}

__global__ __launch_bounds__(256) void k_agg(
    const unsigned* __restrict__ rs, const uintx4* __restrict__ csr,
    const unsigned* __restrict__ xtb, float* __restrict__ out) {
  const int lane = threadIdx.x & 63;
  const int dst = (int)((blockIdx.x * (unsigned)blockDim.x + threadIdx.x) >> 6);
  if (dst >= N_NODES) return;

  const unsigned j0 = rs[dst];
  const unsigned j1 = rs[dst + 1];
  const int deg = (int)(j1 - j0);

  float a0 = 0.f, a1 = 0.f, lsum = 0.f;

  if (deg > 0) {
    const int rounds = (deg + 15) >> 4;
    const int eL = lane & 15;   // edge slot
    const int hB = lane >> 4;   // head (same role in score & accum)

    const uintx4 pad = {0u, 0xfc00fc00u, 0xfc00fc00u, 0u};

    for (int r = 0; r < rounds; ++r) {
      const int j = (int)j0 + r * 16 + eL;
      const uintx4 ent =
          (j < (int)j1) ? __builtin_nontemporal_load(&csr[j]) : pad;
      const float w = __expf(ent_score(ent, hB));  // pad: exp(-inf)=0
      lsum += w;
      const int sx = (int)ent.x;

      int ssrc[16];
#pragma unroll
      for (int jj = 0; jj < 16; ++jj)
        ssrc[jj] = __builtin_amdgcn_readlane(sx, jj);
      unsigned ud[16];
#pragma unroll
      for (int jj = 0; jj < 16; ++jj)
        ud[jj] = xtb[(size_t)ssrc[jj] * 64 + lane];
#define AGG_STEP(JJ)                                                         \
  {                                                                          \
    const float wj = __int_as_float(__builtin_amdgcn_ds_swizzle(             \
        __float_as_int(w), ((JJ) << 5) | 0x10));                             \
    a0 = fmaf(wj, __uint_as_float(ud[JJ] << 16), a0);                        \
    a1 = fmaf(wj, __uint_as_float(ud[JJ] & 0xffff0000u), a1);                \
  }
      AGG_STEP(0)  AGG_STEP(1)  AGG_STEP(2)  AGG_STEP(3)
      AGG_STEP(4)  AGG_STEP(5)  AGG_STEP(6)  AGG_STEP(7)
      AGG_STEP(8)  AGG_STEP(9)  AGG_STEP(10) AGG_STEP(11)
      AGG_STEP(12) AGG_STEP(13) AGG_STEP(14) AGG_STEP(15)
#undef AGG_STEP
    }
    lsum += __shfl_xor(lsum, 1, 64);
    lsum += __shfl_xor(lsum, 2, 64);
    lsum += __shfl_xor(lsum, 4, 64);
    lsum += __shfl_xor(lsum, 8, 64);
  }

  const float inv = 1.0f / (lsum + 1e-10f);
  __builtin_nontemporal_store(a0 * inv, &out[(size_t)dst * 128 + lane * 2 + 0]);
  __builtin_nontemporal_store(a1 * inv, &out[(size_t)dst * 128 + lane * 2 + 1]);
}

extern "C" void kernel_launch(void* const* d_in, const int* in_sizes, int n_in,
                              void* d_out, int out_size, void* d_ws,
                              size_t ws_size, hipStream_t stream) {
  const float* x = (const float*)d_in[0];
  const int* ei = (const int*)d_in[1];
  const float* ea = (const float*)d_in[2];
  const float* W = (const float*)d_in[3];
  const float* a = (const float*)d_in[4];
  float* out = (float*)d_out;

  // workspace layout
  char* p = (char*)d_ws;
  unsigned* xtb = (unsigned*)p;     p += (size_t)N_NODES * 64 * 4;      // 12.8 MB
  uintx4* csr = (uintx4*)p;         p += (size_t)N_EDGES * 16;          // 12.8 MB
  uintx4* stage = (uintx4*)p;       p += (size_t)NBUCK * CAP * 16;      // 16.1 MB
  float* alpha_src = (float*)p;     p += (size_t)N_NODES * 4 * 4;       // 0.8 MB
  float* alpha_dst = (float*)p;     p += (size_t)N_NODES * 4 * 4;       // 0.8 MB
  unsigned* rs = (unsigned*)p;      p += (size_t)(N_NODES + 1) * 4;     // 0.2 MB
  unsigned* bfill = (unsigned*)p;   p += 128 * 4;
  unsigned short* wtg = (unsigned short*)p; p += 128 * 128 * 2;         // 32 KB

  k_wprep<<<128, 128, 0, stream>>>(W, wtg, bfill);
  k_transform<<<(N_NODES + 63) / 64, 256, 0, stream>>>(x, wtg, a, xtb,
                                                       alpha_src, alpha_dst);
  k_binsort<<<NBLK_A, BT, 0, stream>>>(ei, ea, a, alpha_src, alpha_dst, bfill,
                                       stage);
  k_place<<<NBUCK, 1024, 0, stream>>>(bfill, stage, rs, csr);
  k_agg<<<(N_NODES * 64 + 255) / 256, 256, 0, stream>>>(rs, csr, xtb, out);
}